// Round 1
// baseline (54.168 us; speedup 1.0000x reference)
//
#include <hip/hip_runtime.h>

// x: (64, 64, 128, 128) f32; weight: (64, 128, 3, 3) f32; bias: (128,) f32
// out: (64, 128, 1, 1) f32
// stats[b][c][j] j in {full, top(row0), left(col0), corner}
// coeff[o][c][j] from weight[c][o][k][l]:
//   full = sum_kl w ; top = -sum_l w[0][l] ; left = -sum_k w[k][0] ; corner = w[0][0]
// out[b][o] = 2*bias[o] + (2/65536) * sum_{c,j} stats[b][c][j]*coeff[o][c][j]

__global__ __launch_bounds__(256) void stats_kernel(const float* __restrict__ x,
                                                    float* __restrict__ stats) {
    const int bc = blockIdx.x;  // 0..4095  (b*64 + c)
    const float4* img = reinterpret_cast<const float4*>(x + (size_t)bc * 16384);
    const int tid = threadIdx.x;

    float s_full = 0.f, s_top = 0.f, s_left = 0.f, s_corner = 0.f;
    #pragma unroll
    for (int it = 0; it < 16; ++it) {
        const int i = tid + it * 256;          // float4 index, 0..4095
        float4 v = img[i];
        const int e = i << 2;                  // element index
        const float s4 = (v.x + v.y) + (v.z + v.w);
        s_full += s4;
        if (e < 128) s_top += s4;              // row 0 (float4 never crosses rows)
        if ((e & 127) == 0) {                  // col 0
            s_left += v.x;
            if (e == 0) s_corner = v.x;
        }
    }

    // wave (64-lane) reduction
    #pragma unroll
    for (int off = 32; off > 0; off >>= 1) {
        s_full   += __shfl_down(s_full, off);
        s_top    += __shfl_down(s_top, off);
        s_left   += __shfl_down(s_left, off);
        s_corner += __shfl_down(s_corner, off);
    }

    __shared__ float red[4][4];
    const int wave = tid >> 6, lane = tid & 63;
    if (lane == 0) {
        red[wave][0] = s_full;
        red[wave][1] = s_top;
        red[wave][2] = s_left;
        red[wave][3] = s_corner;
    }
    __syncthreads();
    if (tid < 4) {
        stats[bc * 4 + tid] =
            (red[0][tid] + red[1][tid]) + (red[2][tid] + red[3][tid]);
    }
}

__global__ __launch_bounds__(128) void out_kernel(const float* __restrict__ stats,
                                                  const float* __restrict__ weight,
                                                  const float* __restrict__ bias,
                                                  float* __restrict__ out) {
    const int b = blockIdx.x;       // 0..63
    const int o = threadIdx.x;      // 0..127

    __shared__ float st[64][4];
    {
        float* stf = &st[0][0];
        for (int i = threadIdx.x; i < 256; i += 128) stf[i] = stats[b * 256 + i];
    }
    __syncthreads();

    float acc = 0.f;
    #pragma unroll 4
    for (int c = 0; c < 64; ++c) {
        const float* w = weight + ((size_t)c * 128 + o) * 9;
        const float w00 = w[0], w01 = w[1], w02 = w[2];
        const float w10 = w[3], w11 = w[4], w12 = w[5];
        const float w20 = w[6], w21 = w[7], w22 = w[8];
        const float c_full = ((w00 + w01) + (w02 + w10)) + ((w11 + w12) + (w20 + w21)) + w22;
        const float c_top  = -((w00 + w01) + w02);
        const float c_left = -((w00 + w10) + w20);
        acc += st[c][0] * c_full + st[c][1] * c_top + st[c][2] * c_left + st[c][3] * w00;
    }

    const float scale = 2.0f / 65536.0f;
    out[b * 128 + o] = 2.0f * bias[o] + acc * scale;
}

extern "C" void kernel_launch(void* const* d_in, const int* in_sizes, int n_in,
                              void* d_out, int out_size, void* d_ws, size_t ws_size,
                              hipStream_t stream) {
    const float* x      = (const float*)d_in[0];
    const float* weight = (const float*)d_in[1];
    const float* bias   = (const float*)d_in[2];
    float* out   = (float*)d_out;
    float* stats = (float*)d_ws;    // 64*64*4 floats = 64 KiB < ws

    stats_kernel<<<4096, 256, 0, stream>>>(x, stats);
    out_kernel<<<64, 128, 0, stream>>>(stats, weight, bias, out);
}